// Round 1
// baseline (264.461 us; speedup 1.0000x reference)
//
#include <hip/hip_runtime.h>

#define NUM_CLASSES 100000
#define FEAT_DIM    256
#define BATCH       16384
#define ALPHA       0.5f
#define EPS_        1e-6f

__global__ void count_kernel(const int* __restrict__ target, int* __restrict__ counts) {
    int i = blockIdx.x * blockDim.x + threadIdx.x;
    if (i < BATCH) atomicAdd(&counts[target[i]], 1);
}

// One block (256 threads) per sample. Thread d handles feature dim d.
__global__ void update_kernel(const float* __restrict__ centers,
                              const float* __restrict__ features,
                              const int*   __restrict__ target,
                              const int*   __restrict__ counts,
                              float*       __restrict__ out_centers,  // d_out + 1
                              float*       __restrict__ loss_acc) {
    const int i = blockIdx.x;   // sample index
    const int d = threadIdx.x;  // feature dim
    const int t = target[i];    // uniform across block -> broadcast

    const float c = centers[(size_t)t * FEAT_DIM + d];
    const float f = features[(size_t)i * FEAT_DIM + d];
    const float diff = c - f;                  // centers_batch - features
    float sq = diff * diff;                    // (f - c)^2 == diff^2

    const float cnt = (float)counts[t];
    const float upd = (ALPHA * diff) / (cnt + EPS_);
    // serial loop `centers[target[i]] -= update[i]` == scatter-subtract w/ accumulation
    atomicAdd(&out_centers[(size_t)t * FEAT_DIM + d], -upd);

    // block-reduce sq: wave64 shuffle, then 4 wave partials via LDS
    #pragma unroll
    for (int off = 32; off > 0; off >>= 1)
        sq += __shfl_down(sq, off, 64);
    __shared__ float wsum[4];
    const int lane = threadIdx.x & 63;
    const int wid  = threadIdx.x >> 6;
    if (lane == 0) wsum[wid] = sq;
    __syncthreads();
    if (threadIdx.x == 0) {
        atomicAdd(loss_acc, wsum[0] + wsum[1] + wsum[2] + wsum[3]);
    }
}

__global__ void finalize_kernel(const float* __restrict__ loss_acc, float* __restrict__ out) {
    out[0] = loss_acc[0] * (1.0f / ((float)BATCH * (float)FEAT_DIM));
}

extern "C" void kernel_launch(void* const* d_in, const int* in_sizes, int n_in,
                              void* d_out, int out_size, void* d_ws, size_t ws_size,
                              hipStream_t stream) {
    const float* centers  = (const float*)d_in[0];
    const float* features = (const float*)d_in[1];
    const int*   target   = (const int*)d_in[2];

    float* out         = (float*)d_out;
    float* out_centers = out + 1;  // new_centers follows the loss scalar

    int*   counts   = (int*)d_ws;
    float* loss_acc = (float*)((char*)d_ws + (size_t)NUM_CLASSES * sizeof(int));

    // zero counts + loss accumulator (d_ws is poisoned 0xAA, not re-poisoned between replays:
    // we must zero every call — this is deterministic per-call work)
    hipMemsetAsync(d_ws, 0, (size_t)NUM_CLASSES * sizeof(int) + sizeof(float), stream);

    // new_centers starts as a copy of centers (handles the +1 float misalignment too)
    hipMemcpyAsync(out_centers, centers,
                   (size_t)NUM_CLASSES * FEAT_DIM * sizeof(float),
                   hipMemcpyDeviceToDevice, stream);

    count_kernel<<<(BATCH + 255) / 256, 256, 0, stream>>>(target, counts);

    update_kernel<<<BATCH, FEAT_DIM, 0, stream>>>(centers, features, target, counts,
                                                  out_centers, loss_acc);

    finalize_kernel<<<1, 1, 0, stream>>>(loss_acc, out);
}

// Round 2
// 68.690 us; speedup vs baseline: 3.8501x; 3.8501x over previous
//
#include <hip/hip_runtime.h>

#define NUM_CLASSES 100000
#define FEAT_DIM    256
#define BATCH       16384
#define ALPHA       0.5f
#define EPS_        1e-6f

__global__ void count_kernel(const int* __restrict__ target, int* __restrict__ counts) {
    int i = blockIdx.x * blockDim.x + threadIdx.x;
    if (i < BATCH) atomicAdd(&counts[target[i]], 1);
}

// 4 waves per block; one sample per wave; lane l handles dims [4l, 4l+4).
__global__ void update_kernel(const float* __restrict__ centers,
                              const float* __restrict__ features,
                              const int*   __restrict__ target,
                              const int*   __restrict__ counts,
                              float*       __restrict__ out_centers,  // d_out + 1
                              float*       __restrict__ partials) {   // [BATCH]
    const int wave = threadIdx.x >> 6;
    const int lane = threadIdx.x & 63;
    const int i = blockIdx.x * 4 + wave;   // sample index (BATCH % 4 == 0)
    const int t = target[i];               // wave-uniform

    const float4 c = *(const float4*)(centers  + (size_t)t * FEAT_DIM + lane * 4);
    const float4 f = *(const float4*)(features + (size_t)i * FEAT_DIM + lane * 4);
    const float dx = c.x - f.x, dy = c.y - f.y, dz = c.z - f.z, dw = c.w - f.w;
    float sq = dx*dx + dy*dy + dz*dz + dw*dw;

    const int cnt = counts[t];             // wave-uniform
    const float s = -ALPHA / ((float)cnt + EPS_);   // new = c + s*diff

    float* orow = out_centers + (size_t)t * FEAT_DIM + lane * 4;
    if (cnt == 1) {
        // exclusive owner: plain store, no RMW (85% of samples)
        orow[0] = c.x + s * dx;
        orow[1] = c.y + s * dy;
        orow[2] = c.z + s * dz;
        orow[3] = c.w + s * dw;
    } else {
        atomicAdd(&orow[0], s * dx);
        atomicAdd(&orow[1], s * dy);
        atomicAdd(&orow[2], s * dz);
        atomicAdd(&orow[3], s * dw);
    }

    // wave-level reduce of sq, then ONE plain store per sample (no global atomic)
    #pragma unroll
    for (int off = 32; off > 0; off >>= 1)
        sq += __shfl_down(sq, off, 64);
    if (lane == 0) partials[i] = sq;
}

__global__ void reduce_loss(const float* __restrict__ partials, float* __restrict__ out) {
    float s = 0.0f;
    for (int i = threadIdx.x; i < BATCH; i += 1024) s += partials[i];  // 16 each
    #pragma unroll
    for (int off = 32; off > 0; off >>= 1)
        s += __shfl_down(s, off, 64);
    __shared__ float wsum[16];
    const int lane = threadIdx.x & 63;
    const int wid  = threadIdx.x >> 6;
    if (lane == 0) wsum[wid] = s;
    __syncthreads();
    if (threadIdx.x == 0) {
        float tot = 0.0f;
        #pragma unroll
        for (int k = 0; k < 16; ++k) tot += wsum[k];
        out[0] = tot * (1.0f / ((float)BATCH * (float)FEAT_DIM));
    }
}

extern "C" void kernel_launch(void* const* d_in, const int* in_sizes, int n_in,
                              void* d_out, int out_size, void* d_ws, size_t ws_size,
                              hipStream_t stream) {
    const float* centers  = (const float*)d_in[0];
    const float* features = (const float*)d_in[1];
    const int*   target   = (const int*)d_in[2];

    float* out         = (float*)d_out;
    float* out_centers = out + 1;  // new_centers after the loss scalar

    int*   counts   = (int*)d_ws;
    float* partials = (float*)((char*)d_ws + (size_t)NUM_CLASSES * sizeof(int));

    // zero the counts histogram every call (ws is not re-poisoned between replays,
    // but we must not rely on stale state either way)
    hipMemsetAsync(counts, 0, (size_t)NUM_CLASSES * sizeof(int), stream);

    // new_centers starts as a copy of centers
    hipMemcpyAsync(out_centers, centers,
                   (size_t)NUM_CLASSES * FEAT_DIM * sizeof(float),
                   hipMemcpyDeviceToDevice, stream);

    count_kernel<<<(BATCH + 255) / 256, 256, 0, stream>>>(target, counts);

    update_kernel<<<BATCH / 4, 256, 0, stream>>>(centers, features, target, counts,
                                                 out_centers, partials);

    reduce_loss<<<1, 1024, 0, stream>>>(partials, out);
}